// Round 7
// baseline (489.844 us; speedup 1.0000x reference)
//
#include <hip/hip_runtime.h>
#include <hip/hip_bf16.h>
#include <stdint.h>

// ---------------------------------------------------------------------------
// HeadAttention: Q=xq*W^T+b, K=xk*W^T+b, V=xv*W^T+b (same W,b),
// O = softmax(causal(Q K^T / 32)) V.    B=4, S=2048, E=1024, fp32 in/out.
// R7: LDS-free register-direct MFMA GEMMs. Every 64-thread block is one
// independent wave computing a 64x64 tile; A/B fragments are loaded straight
// from global (k-major both sides -> 16B/lane frag loads, full 64B sectors),
// ping-pong double-buffered in registers. No barriers anywhere.
// No softmax pass (P=exp unnorm bf16 + atomic row sums; PV normalizes).
// ---------------------------------------------------------------------------

typedef __attribute__((ext_vector_type(8))) short bf16x8;
typedef __attribute__((ext_vector_type(4))) float floatx4;

#define DEVI static __device__ __forceinline__

static constexpr int S_ = 2048;
static constexpr int E_ = 1024;
static constexpr int BATCH = 4;
static constexpr int N4X = 8192 * 1024 / 4;  // float4 count per X input

DEVI unsigned short f2b(float f) {
  union { float f; unsigned u; } v; v.f = f;
  return (unsigned short)((v.u + 0x7FFFu + ((v.u >> 16) & 1u)) >> 16); // RNE
}

// load 4 A- or B-fragments (rows i*16+lrow, 16B each) at element offset k0
DEVI void load_frags(bf16x8 (&fr)[4], const unsigned short* __restrict__ base,
                     const uint32_t (&off)[4], uint32_t k0) {
#pragma unroll
  for (int i = 0; i < 4; ++i)
    fr[i] = *(const bf16x8*)(base + (off[i] + k0));
}

DEVI void mfma16(const bf16x8 (&a)[4], const bf16x8 (&b)[4],
                 floatx4 (&acc)[4][4]) {
#pragma unroll
  for (int mi = 0; mi < 4; ++mi)
#pragma unroll
    for (int ni = 0; ni < 4; ++ni)
      acc[mi][ni] = __builtin_amdgcn_mfma_f32_16x16x32_bf16(
          a[mi], b[ni], acc[mi][ni], 0, 0, 0);
}

// K-loop core: 64x64 tile, nSteps double-steps of 64 K, register ping-pong.
DEVI void core64(const unsigned short* __restrict__ A,
                 const unsigned short* __restrict__ B, int lda, int ldb,
                 int nSteps, int lane, floatx4 (&acc)[4][4]) {
  const int lrow = lane & 15, lk8 = (lane >> 4) * 8;
  uint32_t ao[4], bo[4];
#pragma unroll
  for (int i = 0; i < 4; ++i) {
    ao[i] = (uint32_t)(i * 16 + lrow) * lda + lk8;
    bo[i] = (uint32_t)(i * 16 + lrow) * ldb + lk8;
  }
  bf16x8 a0[4], b0[4], a1[4], b1[4];
  load_frags(a0, A, ao, 0);
  load_frags(b0, B, bo, 0);
  for (int s = 0; s < nSteps; ++s) {
    load_frags(a1, A, ao, (uint32_t)(2 * s + 1) * 32);
    load_frags(b1, B, bo, (uint32_t)(2 * s + 1) * 32);
    mfma16(a0, b0, acc);
    if (s + 1 < nSteps) {
      load_frags(a0, A, ao, (uint32_t)(2 * s + 2) * 32);
      load_frags(b0, B, bo, (uint32_t)(2 * s + 2) * 32);
    }
    mfma16(a1, b1, acc);
  }
}

// fp32 -> bf16 convert: xq|xk|xv -> Xb, Wq -> Wb, one dispatch
__global__ void cvt_all(const float* __restrict__ xq,
                        const float* __restrict__ xk,
                        const float* __restrict__ xv,
                        const float* __restrict__ Wq,
                        unsigned short* __restrict__ Xb,
                        unsigned short* __restrict__ Wb) {
  int i = blockIdx.x * blockDim.x + threadIdx.x;
  const float4* src;
  ushort4* dst;
  if (i < 3 * N4X) {
    int seg = i / N4X, off = i - seg * N4X;
    const float* s = (seg == 0) ? xq : (seg == 1) ? xk : xv;
    src = (const float4*)s + off;
    dst = (ushort4*)(Xb + (size_t)seg * 8192 * 1024) + off;
  } else {
    int off = i - 3 * N4X;  // [0, 1024*1024/4)
    src = (const float4*)Wq + off;
    dst = (ushort4*)Wb + off;
  }
  float4 v = *src;
  ushort4 o;
  o.x = f2b(v.x); o.y = f2b(v.y); o.z = f2b(v.z); o.w = f2b(v.w);
  *dst = o;
}

// ---------------------------------------------------------------------------
// Fused QKV linear: C = Xb * Wb^T + bias, Xb = [3*8192, 1024].
// 6144 one-wave blocks (64x64 tiles). XCD swizzle: xcd=l&7, t=l>>3,
// bn64=t&15, strip=(t>>4)*8+xcd — all 16 bn-blocks of one 64-row A-strip on
// one XCD (A fetched once per XCD; W is L2-resident per XCD).
// V (input 2) stored transposed: Vt[b][e][s].
// ---------------------------------------------------------------------------
__global__ __launch_bounds__(64) void gemm_qkv(
    const unsigned short* __restrict__ Xb, const unsigned short* __restrict__ Wb,
    const float* __restrict__ bias, unsigned short* __restrict__ Qb,
    unsigned short* __restrict__ Kb, unsigned short* __restrict__ Vt) {
  const int l = blockIdx.x;
  const int xcd = l & 7, t = l >> 3;
  const int bn64 = t & 15;
  const int strip = (t >> 4) * 8 + xcd;  // [0,384)
  const int row0 = strip * 64;           // [0,24576)
  const int input = row0 >> 13;
  const unsigned short* A = Xb + (size_t)row0 * 1024;
  const unsigned short* W = Wb + (size_t)bn64 * 64 * 1024;
  const int lane = threadIdx.x;

  floatx4 acc[4][4] = {};
  core64(A, W, 1024, 1024, 16, lane, acc);

  unsigned short* C = (input == 0) ? Qb : (input == 1) ? Kb : Vt;
  const int lrow = lane & 15, rb = (lane >> 4) * 4;
  const int rloc = row0 & 8191;
#pragma unroll
  for (int mi = 0; mi < 4; ++mi)
#pragma unroll
    for (int ni = 0; ni < 4; ++ni) {
      int gcol = bn64 * 64 + ni * 16 + lrow;
      float bv = bias[gcol];
#pragma unroll
      for (int r = 0; r < 4; ++r) {
        int grow = rloc + mi * 16 + rb + r;
        unsigned short val = f2b(acc[mi][ni][r] + bv);
        if (input == 2) {
          int b = grow >> 11, s = grow & 2047;
          C[((size_t)b * 1024 + gcol) * 2048 + s] = val;
        } else {
          C[(size_t)grow * 1024 + gcol] = val;
        }
      }
    }
}

// ---------------------------------------------------------------------------
// Scores+exp: P[z][q,k] = exp(Q.K/32) (unnorm bf16; 0 where k>q), lsum[q] +=
// row sums (atomic). 2112 one-wave blocks: lower-tri 64-tiles (528 per z).
// xcd=l&7, t=l>>3; g=xcd*264+t -> contiguous tri-range per XCD (Q/K strips
// localized, 2 XCDs per batch).
// ---------------------------------------------------------------------------
__global__ __launch_bounds__(64) void gemm_scores_exp(
    const unsigned short* __restrict__ Qb,
    const unsigned short* __restrict__ Kb, unsigned short* __restrict__ P,
    float* __restrict__ lsum) {
  const int l = blockIdx.x;
  const int xcd = l & 7, t = l >> 3;
  const int g = xcd * 264 + t;       // [0,2112)
  const int z = g / 528, r0 = g % 528;
  int bm = (int)((sqrtf(8.0f * r0 + 1.0f) - 1.0f) * 0.5f);
  while ((bm + 1) * (bm + 2) / 2 <= r0) ++bm;
  while (bm * (bm + 1) / 2 > r0) --bm;
  const int bn = r0 - bm * (bm + 1) / 2;  // bn <= bm

  const unsigned short* A = Qb + ((size_t)z * S_ + bm * 64) * E_;
  const unsigned short* Bt = Kb + ((size_t)z * S_ + bn * 64) * E_;
  const int lane = threadIdx.x;

  floatx4 acc[4][4] = {};
  core64(A, Bt, E_, E_, 16, lane, acc);

  const int lrow = lane & 15, rb = (lane >> 4) * 4;
  const bool diag = (bm == bn);
#pragma unroll
  for (int mi = 0; mi < 4; ++mi)
#pragma unroll
    for (int r = 0; r < 4; ++r) {
      const int grow = bm * 64 + mi * 16 + rb + r;
      float rsum = 0.f;
#pragma unroll
      for (int ni = 0; ni < 4; ++ni) {
        const int gcol = bn * 64 + ni * 16 + lrow;
        float p = __expf(acc[mi][ni][r] * 0.03125f);
        if (diag && gcol > grow) p = 0.f;
        P[((size_t)z * S_ + grow) * S_ + gcol] = f2b(p);
        rsum += p;
      }
#pragma unroll
      for (int off = 1; off < 16; off <<= 1) rsum += __shfl_xor(rsum, off);
      if (lrow == 0) atomicAdd(&lsum[z * S_ + grow], rsum);
    }
}

// ---------------------------------------------------------------------------
// PV: out[z][q,e] = (P V) / l[q], K truncated at (bm+1)*64 (causal zeros in
// the diag tile cover the remainder). 2048 one-wave blocks, balanced:
// xcd=l&7, t=l>>3, bn=t&15, u=t>>4; p=u*8+xcd; bm=31-(p>>2) (heavy first,
// round-robin over XCDs, +-3% balance), z=p&3.
// ---------------------------------------------------------------------------
__global__ __launch_bounds__(64) void gemm_pv(
    const unsigned short* __restrict__ Pb,
    const unsigned short* __restrict__ Vt, const float* __restrict__ lsum,
    float* __restrict__ Out) {
  const int l = blockIdx.x;
  const int xcd = l & 7, t = l >> 3;
  const int bn = t & 15, u = t >> 4;
  const int p = u * 8 + xcd;       // [0,128)
  const int bm = 31 - (p >> 2);
  const int z = p & 3;

  const unsigned short* A = Pb + ((size_t)z * S_ + bm * 64) * S_;
  const unsigned short* Bt = Vt + ((size_t)z * E_ + bn * 64) * S_;
  float* C = Out + (size_t)z * S_ * E_;
  const int lane = threadIdx.x;

  floatx4 acc[4][4] = {};
  core64(A, Bt, S_, S_, bm + 1, lane, acc);  // (bm+1) x 64-K double-steps

  const int lrow = lane & 15, rb = (lane >> 4) * 4;
#pragma unroll
  for (int mi = 0; mi < 4; ++mi)
#pragma unroll
    for (int r = 0; r < 4; ++r) {
      const int grow = bm * 64 + mi * 16 + rb + r;
      const float inv = 1.0f / lsum[z * S_ + grow];
#pragma unroll
      for (int ni = 0; ni < 4; ++ni) {
        const int gcol = bn * 64 + ni * 16 + lrow;
        C[(size_t)grow * E_ + gcol] = acc[mi][ni][r] * inv;
      }
    }
}

// ---------------------------------------------------------------------------
extern "C" void kernel_launch(void* const* d_in, const int* in_sizes, int n_in,
                              void* d_out, int out_size, void* d_ws,
                              size_t ws_size, hipStream_t stream) {
  (void)in_sizes; (void)n_in; (void)out_size; (void)ws_size;
  const float* xq = (const float*)d_in[0];
  const float* xk = (const float*)d_in[1];
  const float* xv = (const float*)d_in[2];
  const float* Wq = (const float*)d_in[3];
  const float* bq = (const float*)d_in[4];
  // d_in[5] att_mask: exact triu(k=1) causal mask, handled analytically.
  float* out = (float*)d_out;

  // workspace (<= 114 MB used):
  //  [0,48M):  Xb (bf16 3*8192*1024) during cvt+QKV; then reused as
  //            P (bf16 4*2048*2048 = 32M) by scores/pv.
  //  [48,50M): Wb  [50,66M): Qb  [66,82M): Kb  [82,98M): Vt
  //  [98M, 98M+32K): l (fp32 row sums)
  unsigned short* base16 = (unsigned short*)d_ws;
  unsigned short* Xb = base16;
  unsigned short* P = base16;
  unsigned short* Wb = base16 + (size_t)24 * 1024 * 1024;  // +48MB
  unsigned short* Qb = Wb + (size_t)1024 * 1024;
  unsigned short* Kb = Qb + (size_t)8192 * 1024;
  unsigned short* Vt = Kb + (size_t)8192 * 1024;
  float* lsum = (float*)(Vt + (size_t)8192 * 1024);  // +98MB, 32KB

  hipMemsetAsync(lsum, 0, BATCH * S_ * sizeof(float), stream);

  const int n4tot = 3 * N4X + 1024 * 1024 / 4;
  cvt_all<<<n4tot / 256, 256, 0, stream>>>(xq, xk, xv, Wq, Xb, Wb);

  gemm_qkv<<<6144, 64, 0, stream>>>(Xb, Wb, bq, Qb, Kb, Vt);
  gemm_scores_exp<<<2112, 64, 0, stream>>>(Qb, Kb, P, lsum);
  gemm_pv<<<2048, 64, 0, stream>>>(P, Vt, lsum, out);
}